// Round 4
// baseline (352.896 us; speedup 1.0000x reference)
//
#include <hip/hip_runtime.h>

typedef _Float16 f16;
typedef _Float16 f16x8 __attribute__((ext_vector_type(8)));
typedef float    f32x4 __attribute__((ext_vector_type(4)));

#define H 128

// ============================================================================
// Kernel 0: convert W1 (128x256 f32) and W2 (128x128 f32) to f16 in
// MFMA-fragment-contiguous layout:
//   W1h[(h*32 + kt*8 + nt)*512 + lane*8 + i] = W1[lr+16nt][h*128 + kt*32 + lg*8 + i]
//   W2h[(kt*8 + nt)*512 + lane*8 + i]        = W2[lr+16nt][kt*32 + lg*8 + i]
// (lane = lg*16+lr).  A fragment load is then one coalesced 16 B load.
// Grid: 24 blocks x 256 = 6144 threads = 96 frags x 64 lanes.
// ============================================================================
__global__ __launch_bounds__(256) void convert_weights(
    const float* __restrict__ W1, const float* __restrict__ W2,
    f16* __restrict__ W1h, f16* __restrict__ W2h)
{
    const int gid    = blockIdx.x * 256 + threadIdx.x;
    const int fi_all = gid >> 6;
    const int lane   = gid & 63;
    const int lg = lane >> 4, lr = lane & 15;
    const float* src;
    f16* dst;
    if (fi_all < 64) {
        const int h = fi_all >> 5, kt = (fi_all >> 3) & 3, nt = fi_all & 7;
        src = W1 + (size_t)(lr + 16 * nt) * (2 * H) + h * H + kt * 32 + lg * 8;
        dst = W1h + fi_all * 512 + lane * 8;
    } else {
        const int fi = fi_all - 64;
        const int kt = fi >> 3, nt = fi & 7;
        src = W2 + (size_t)(lr + 16 * nt) * H + kt * 32 + lg * 8;
        dst = W2h + fi * 512 + lane * 8;
    }
    const float4 x0 = *(const float4*)src;
    const float4 x1 = *(const float4*)(src + 4);
    *(f16x8*)dst = (f16x8){(f16)x0.x, (f16)x0.y, (f16)x0.z, (f16)x0.w,
                           (f16)x1.x, (f16)x1.y, (f16)x1.z, (f16)x1.w};
}

// ============================================================================
// Kernel A: precompute U = zu@W1u^T + b1 (f16), R = zr@W1r^T (f16).
// One block = 64 output rows, 4 waves x 16 rows, MFMA 16x16x32 f16.
// B-frags are single 16 B loads from fragment-layout W1h (L1/L2-hot).
// ============================================================================
__global__ __launch_bounds__(256) void precompute_kernel(
    const float* __restrict__ zu, const float* __restrict__ zr,
    const f16* __restrict__ W1h, const float* __restrict__ b1,
    f16* __restrict__ U, f16* __restrict__ R,
    int nU, int nR, int nUblk)
{
    const int bid  = blockIdx.x;
    const bool isU = bid < nUblk;
    const float* src  = isU ? zu : zr;
    f16*        dst   = isU ? U : R;
    const int   nrows = isU ? nU : nR;
    const int   base  = (isU ? bid : bid - nUblk) * 64;
    const int   hsel  = isU ? 0 : 32;   // W1h frag-block offset (user/rest half)

    const int tid  = threadIdx.x;
    const int wid  = tid >> 6;
    const int lane = tid & 63;
    const int lg   = lane >> 4;
    const int lr   = lane & 15;

    // ---- A fragments: 16 rows of src per wave, f32 -> f16 ----
    const int arow   = base + wid * 16 + lr;
    const int arow_c = arow < nrows ? arow : (nrows - 1);
    f16x8 afr[4];
    #pragma unroll
    for (int kt = 0; kt < 4; ++kt) {
        const float* p = src + (size_t)arow_c * H + kt * 32 + lg * 8;
        const float4 x0 = *(const float4*)p;
        const float4 x1 = *(const float4*)(p + 4);
        afr[kt] = (f16x8){(f16)x0.x, (f16)x0.y, (f16)x0.z, (f16)x0.w,
                          (f16)x1.x, (f16)x1.y, (f16)x1.z, (f16)x1.w};
    }

    // ---- accumulators, bias folded for U ----
    f32x4 acc[8];
    #pragma unroll
    for (int nt = 0; nt < 8; ++nt) {
        const float b = isU ? b1[lr + 16 * nt] : 0.0f;
        acc[nt] = (f32x4){b, b, b, b};
    }

    // ---- MFMA: 8 independent 16 B B-loads per kt, then 8 MFMAs ----
    #pragma unroll
    for (int kt = 0; kt < 4; ++kt) {
        f16x8 bf[8];
        #pragma unroll
        for (int nt = 0; nt < 8; ++nt)
            bf[nt] = *(const f16x8*)(W1h + (size_t)(hsel + kt * 8 + nt) * 512 + lane * 8);
        #pragma unroll
        for (int nt = 0; nt < 8; ++nt)
            acc[nt] = __builtin_amdgcn_mfma_f32_16x16x32_f16(afr[kt], bf[nt], acc[nt], 0, 0, 0);
    }

    // ---- repack via LDS, coalesced 64 B f16 stores ----
    __shared__ f16 lds[64][136];
    #pragma unroll
    for (int nt = 0; nt < 8; ++nt)
        #pragma unroll
        for (int r = 0; r < 4; ++r)
            lds[wid * 16 + lg * 4 + r][lr + 16 * nt] = (f16)acc[nt][r];
    __syncthreads();

    const int srow = tid >> 2, q = tid & 3;
    const int grow = base + srow;
    if (grow < nrows) {
        const uint4* s = (const uint4*)&lds[srow][q * 32];
        uint4* d = (uint4*)(dst + (size_t)grow * H + q * 32);
        d[0] = s[0];
        d[1] = s[1];
        d[2] = s[2];
        d[3] = s[3];
    }
}

// ============================================================================
// Kernel B: per edge  out = W3·relu(W2·relu(U[row]+R[col]) + b2) + b3
// 64 edges/block (4 waves x 16); W2 fragments staged once in 32 KB LDS and
// read per tile via contiguous ds_read_b128; grid-stride with index prefetch.
// ============================================================================
__global__ __launch_bounds__(256, 4) void edge_kernel(
    const int* __restrict__ row, const int* __restrict__ col,
    const f16* __restrict__ U, const f16* __restrict__ R,
    const f16* __restrict__ W2h, const float* __restrict__ b2,
    const float* __restrict__ W3, const float* __restrict__ b3,
    float* __restrict__ out, int nEdge, int nTiles)
{
    __shared__ f16 w2s[32 * 512];   // 32 KB: W2 fragments, frag-contiguous

    const int tid  = threadIdx.x;
    const int wid  = tid >> 6;
    const int lane = tid & 63;
    const int lg   = lane >> 4;
    const int lr   = lane & 15;

    // ---- stage W2h -> LDS (linear copy, 128 B/thread) ----
    {
        const uint4* s = (const uint4*)W2h;
        uint4* d = (uint4*)w2s;
        #pragma unroll
        for (int i = 0; i < 8; ++i) d[tid + 256 * i] = s[tid + 256 * i];
    }

    float b2v[8], w3v[8];
    #pragma unroll
    for (int nt = 0; nt < 8; ++nt) {
        b2v[nt] = b2[lr + 16 * nt];
        w3v[nt] = W3[lr + 16 * nt];
    }
    const float b3s = b3[0];
    __syncthreads();

    const int stride = gridDim.x;
    int t = blockIdx.x;
    if (t >= nTiles) return;

    // indices for first tile
    int e0 = t * 64 + wid * 16 + lr;
    e0 = e0 < nEdge ? e0 : (nEdge - 1);
    int ri = row[e0], ci = col[e0];

    for (; t < nTiles; t += stride) {
        // ---- prefetch indices for next tile ----
        const int tn = t + stride;
        int riN = 0, ciN = 0;
        if (tn < nTiles) {
            int en = tn * 64 + wid * 16 + lr;
            en = en < nEdge ? en : (nEdge - 1);
            riN = row[en];
            ciN = col[en];
        }

        // ---- gather U/R rows, h1 = relu(U+R) into A-fragments ----
        f16x8 fr[4];
        #pragma unroll
        for (int kt = 0; kt < 4; ++kt) {
            const f16x8 u = *(const f16x8*)(U + (size_t)ri * H + kt * 32 + lg * 8);
            const f16x8 r = *(const f16x8*)(R + (size_t)ci * H + kt * 32 + lg * 8);
            f16x8 s = u + r;
            #pragma unroll
            for (int i = 0; i < 8; ++i) s[i] = s[i] > (f16)0 ? s[i] : (f16)0;
            fr[kt] = s;
        }

        // ---- layer 2 MFMA, W2 frags from LDS ----
        f32x4 acc[8];
        #pragma unroll
        for (int nt = 0; nt < 8; ++nt) acc[nt] = (f32x4){b2v[nt], b2v[nt], b2v[nt], b2v[nt]};
        #pragma unroll
        for (int kt = 0; kt < 4; ++kt) {
            f16x8 wf[8];
            #pragma unroll
            for (int nt = 0; nt < 8; ++nt)
                wf[nt] = *(const f16x8*)&w2s[(kt * 8 + nt) * 512 + lane * 8];
            #pragma unroll
            for (int nt = 0; nt < 8; ++nt)
                acc[nt] = __builtin_amdgcn_mfma_f32_16x16x32_f16(fr[kt], wf[nt], acc[nt], 0, 0, 0);
        }

        // ---- epilogue: relu -> *w3 -> reduce across 16 lanes -> store ----
        float s0 = 0.f, s1 = 0.f, s2 = 0.f, s3 = 0.f;
        #pragma unroll
        for (int nt = 0; nt < 8; ++nt) {
            const f32x4 a = acc[nt];
            s0 += fmaxf(a[0], 0.f) * w3v[nt];
            s1 += fmaxf(a[1], 0.f) * w3v[nt];
            s2 += fmaxf(a[2], 0.f) * w3v[nt];
            s3 += fmaxf(a[3], 0.f) * w3v[nt];
        }
        #pragma unroll
        for (int m = 1; m < 16; m <<= 1) {
            s0 += __shfl_xor(s0, m);
            s1 += __shfl_xor(s1, m);
            s2 += __shfl_xor(s2, m);
            s3 += __shfl_xor(s3, m);
        }
        if (lr == 0) {
            const int ebase = t * 64 + wid * 16 + lg * 4;
            if (ebase + 0 < nEdge) out[ebase + 0] = s0 + b3s;
            if (ebase + 1 < nEdge) out[ebase + 1] = s1 + b3s;
            if (ebase + 2 < nEdge) out[ebase + 2] = s2 + b3s;
            if (ebase + 3 < nEdge) out[ebase + 3] = s3 + b3s;
        }

        ri = riN;
        ci = ciN;
    }
}

// ============================================================================
// Fallback: round-1 fp32 kernel (used only if ws_size is too small)
// ============================================================================
#define TILE 16
__global__ __launch_bounds__(256) void edgedec_f32(
    const float* __restrict__ z_user, const float* __restrict__ z_rest,
    const int* __restrict__ row, const int* __restrict__ col,
    const float* __restrict__ W1, const float* __restrict__ b1,
    const float* __restrict__ W2, const float* __restrict__ b2,
    const float* __restrict__ W3, const float* __restrict__ b3,
    float* __restrict__ out, int nEdge)
{
    __shared__ float zt[TILE][2 * H];
    __shared__ float h1t[TILE][H];
    __shared__ float part[TILE][16];
    const int tid  = threadIdx.x;
    const int base = blockIdx.x * TILE;
    {
        const int e0 = tid >> 6, half = (tid >> 5) & 1, q = tid & 31;
        #pragma unroll
        for (int it = 0; it < TILE / 4; ++it) {
            const int e = e0 + it * 4, ge = base + e;
            if (ge < nEdge) {
                const float* src = half ? (z_rest + (size_t)col[ge] * H)
                                        : (z_user + (size_t)row[ge] * H);
                *(float4*)&zt[e][half * H + q * 4] = *(const float4*)(src + q * 4);
            }
        }
    }
    __syncthreads();
    const int j = tid & (H - 1), g = tid >> 7;
    float acc[8];
    {
        const float bj = b1[j];
        #pragma unroll
        for (int e = 0; e < 8; ++e) acc[e] = bj;
        const float4* wp = (const float4*)(W1 + (size_t)j * (2 * H));
        for (int k4 = 0; k4 < (2 * H) / 4; ++k4) {
            const float4 w = wp[k4];
            #pragma unroll
            for (int e = 0; e < 8; ++e) {
                const float4 z = *(const float4*)&zt[g * 8 + e][k4 * 4];
                acc[e] = fmaf(w.x, z.x, acc[e]); acc[e] = fmaf(w.y, z.y, acc[e]);
                acc[e] = fmaf(w.z, z.z, acc[e]); acc[e] = fmaf(w.w, z.w, acc[e]);
            }
        }
        #pragma unroll
        for (int e = 0; e < 8; ++e) h1t[g * 8 + e][j] = fmaxf(acc[e], 0.0f);
    }
    __syncthreads();
    {
        const float bj = b2[j];
        #pragma unroll
        for (int e = 0; e < 8; ++e) acc[e] = bj;
        const float4* wp = (const float4*)(W2 + (size_t)j * H);
        for (int k4 = 0; k4 < H / 4; ++k4) {
            const float4 w = wp[k4];
            #pragma unroll
            for (int e = 0; e < 8; ++e) {
                const float4 h = *(const float4*)&h1t[g * 8 + e][k4 * 4];
                acc[e] = fmaf(w.x, h.x, acc[e]); acc[e] = fmaf(w.y, h.y, acc[e]);
                acc[e] = fmaf(w.z, h.z, acc[e]); acc[e] = fmaf(w.w, h.w, acc[e]);
            }
        }
        const float w3j = W3[j];
        __syncthreads();
        #pragma unroll
        for (int e = 0; e < 8; ++e) h1t[g * 8 + e][j] = w3j * fmaxf(acc[e], 0.0f);
    }
    __syncthreads();
    {
        const int e = tid >> 4, p = tid & 15;
        float s = 0.0f;
        #pragma unroll
        for (int i = 0; i < 8; ++i) s += h1t[e][p * 8 + i];
        part[e][p] = s;
    }
    __syncthreads();
    if (tid < TILE) {
        const int ge = base + tid;
        if (ge < nEdge) {
            float s = b3[0];
            #pragma unroll
            for (int i = 0; i < 16; ++i) s += part[tid][i];
            out[ge] = s;
        }
    }
}

extern "C" void kernel_launch(void* const* d_in, const int* in_sizes, int n_in,
                              void* d_out, int out_size, void* d_ws, size_t ws_size,
                              hipStream_t stream) {
    const float* z_user = (const float*)d_in[0];
    const float* z_rest = (const float*)d_in[1];
    const int*   row    = (const int*)d_in[2];
    const int*   col    = (const int*)d_in[3];
    const float* W1     = (const float*)d_in[4];
    const float* b1     = (const float*)d_in[5];
    const float* W2     = (const float*)d_in[6];
    const float* b2     = (const float*)d_in[7];
    const float* W3     = (const float*)d_in[8];
    const float* b3     = (const float*)d_in[9];
    float* out = (float*)d_out;

    const int nU    = in_sizes[0] / H;
    const int nR    = in_sizes[1] / H;
    const int nEdge = in_sizes[2];

    const size_t uBytes  = (size_t)nU * H * sizeof(f16);
    const size_t rBytes  = (size_t)nR * H * sizeof(f16);
    const size_t w2Bytes = (size_t)H * H * sizeof(f16);
    const size_t w1Bytes = (size_t)H * 2 * H * sizeof(f16);
    const size_t need    = uBytes + rBytes + w2Bytes + w1Bytes;

    if (ws_size < need) {
        const int nBlocks = (nEdge + TILE - 1) / TILE;
        hipLaunchKernelGGL(edgedec_f32, dim3(nBlocks), dim3(256), 0, stream,
                           z_user, z_rest, row, col, W1, b1, W2, b2, W3, b3, out, nEdge);
        return;
    }

    f16* U   = (f16*)d_ws;
    f16* R   = (f16*)((char*)d_ws + uBytes);
    f16* W2h = (f16*)((char*)d_ws + uBytes + rBytes);
    f16* W1h = (f16*)((char*)d_ws + uBytes + rBytes + w2Bytes);

    // kernel 0: weight conversion (96 frags x 64 lanes = 24 blocks x 256)
    hipLaunchKernelGGL(convert_weights, dim3(24), dim3(256), 0, stream,
                       W1, W2, W1h, W2h);

    const int nUblk = (nU + 63) / 64;
    const int nRblk = (nR + 63) / 64;
    hipLaunchKernelGGL(precompute_kernel, dim3(nUblk + nRblk), dim3(256), 0, stream,
                       z_user, z_rest, W1h, b1, U, R, nU, nR, nUblk);

    const int nTiles = (nEdge + 63) / 64;
    const int grid   = nTiles < 1024 ? nTiles : 1024;
    hipLaunchKernelGGL(edge_kernel, dim3(grid), dim3(256), 0, stream,
                       row, col, U, R, W2h, b2, W3, b3, out, nEdge, nTiles);
}

// Round 5
// 118.470 us; speedup vs baseline: 2.9788x; 2.9788x over previous
//
#include <hip/hip_runtime.h>

typedef _Float16 f16;
typedef _Float16 f16x8 __attribute__((ext_vector_type(8)));
typedef float    f32x4 __attribute__((ext_vector_type(4)));

#define H 128

// ============================================================================
// Kernel 0: convert W1 (128x256 f32) and W2 (128x128 f32) to f16 in
// MFMA-fragment-contiguous layout:
//   W1h[(h*32 + kt*8 + nt)*512 + lane*8 + i] = W1[lr+16nt][h*128 + kt*32 + lg*8 + i]
//   W2h[(kt*8 + nt)*512 + lane*8 + i]        = W2[lr+16nt][kt*32 + lg*8 + i]
// (lane = lg*16+lr).  A fragment load is then one coalesced 16 B load.
// ============================================================================
__global__ __launch_bounds__(256) void convert_weights(
    const float* __restrict__ W1, const float* __restrict__ W2,
    f16* __restrict__ W1h, f16* __restrict__ W2h)
{
    const int gid    = blockIdx.x * 256 + threadIdx.x;
    const int fi_all = gid >> 6;
    const int lane   = gid & 63;
    const int lg = lane >> 4, lr = lane & 15;
    const float* src;
    f16* dst;
    if (fi_all < 64) {
        const int h = fi_all >> 5, kt = (fi_all >> 3) & 3, nt = fi_all & 7;
        src = W1 + (size_t)(lr + 16 * nt) * (2 * H) + h * H + kt * 32 + lg * 8;
        dst = W1h + fi_all * 512 + lane * 8;
    } else {
        const int fi = fi_all - 64;
        const int kt = fi >> 3, nt = fi & 7;
        src = W2 + (size_t)(lr + 16 * nt) * H + kt * 32 + lg * 8;
        dst = W2h + fi * 512 + lane * 8;
    }
    const float4 x0 = *(const float4*)src;
    const float4 x1 = *(const float4*)(src + 4);
    *(f16x8*)dst = (f16x8){(f16)x0.x, (f16)x0.y, (f16)x0.z, (f16)x0.w,
                           (f16)x1.x, (f16)x1.y, (f16)x1.z, (f16)x1.w};
}

// ============================================================================
// Kernel A: precompute U = zu@W1u^T + b1 (f16), R = zr@W1r^T (f16).
// One block = 64 output rows, 4 waves x 16 rows, MFMA 16x16x32 f16.
// B-frags are single 16 B loads from fragment-layout W1h (L1/L2-hot).
// (R4-measured ~33 us — keep.)
// ============================================================================
__global__ __launch_bounds__(256) void precompute_kernel(
    const float* __restrict__ zu, const float* __restrict__ zr,
    const f16* __restrict__ W1h, const float* __restrict__ b1,
    f16* __restrict__ U, f16* __restrict__ R,
    int nU, int nR, int nUblk)
{
    const int bid  = blockIdx.x;
    const bool isU = bid < nUblk;
    const float* src  = isU ? zu : zr;
    f16*        dst   = isU ? U : R;
    const int   nrows = isU ? nU : nR;
    const int   base  = (isU ? bid : bid - nUblk) * 64;
    const int   hsel  = isU ? 0 : 32;

    const int tid  = threadIdx.x;
    const int wid  = tid >> 6;
    const int lane = tid & 63;
    const int lg   = lane >> 4;
    const int lr   = lane & 15;

    const int arow   = base + wid * 16 + lr;
    const int arow_c = arow < nrows ? arow : (nrows - 1);
    f16x8 afr[4];
    #pragma unroll
    for (int kt = 0; kt < 4; ++kt) {
        const float* p = src + (size_t)arow_c * H + kt * 32 + lg * 8;
        const float4 x0 = *(const float4*)p;
        const float4 x1 = *(const float4*)(p + 4);
        afr[kt] = (f16x8){(f16)x0.x, (f16)x0.y, (f16)x0.z, (f16)x0.w,
                          (f16)x1.x, (f16)x1.y, (f16)x1.z, (f16)x1.w};
    }

    f32x4 acc[8];
    #pragma unroll
    for (int nt = 0; nt < 8; ++nt) {
        const float b = isU ? b1[lr + 16 * nt] : 0.0f;
        acc[nt] = (f32x4){b, b, b, b};
    }

    #pragma unroll
    for (int kt = 0; kt < 4; ++kt) {
        f16x8 bf[8];
        #pragma unroll
        for (int nt = 0; nt < 8; ++nt)
            bf[nt] = *(const f16x8*)(W1h + (size_t)(hsel + kt * 8 + nt) * 512 + lane * 8);
        #pragma unroll
        for (int nt = 0; nt < 8; ++nt)
            acc[nt] = __builtin_amdgcn_mfma_f32_16x16x32_f16(afr[kt], bf[nt], acc[nt], 0, 0, 0);
    }

    __shared__ f16 lds[64][136];
    #pragma unroll
    for (int nt = 0; nt < 8; ++nt)
        #pragma unroll
        for (int r = 0; r < 4; ++r)
            lds[wid * 16 + lg * 4 + r][lr + 16 * nt] = (f16)acc[nt][r];
    __syncthreads();

    const int srow = tid >> 2, q = tid & 3;
    const int grow = base + srow;
    if (grow < nrows) {
        const uint4* s = (const uint4*)&lds[srow][q * 32];
        uint4* d = (uint4*)(dst + (size_t)grow * H + q * 32);
        d[0] = s[0];
        d[1] = s[1];
        d[2] = s[2];
        d[3] = s[3];
    }
}

// ============================================================================
// Kernel B: per edge  out = W3·relu(W2·relu(U[row]+R[col]) + b2) + b3
// R3 structure verbatim (measured 97 us): 64 edges/block (4 waves x 16),
// gather straight into A-fragments, W2 fragments register-resident,
// grid-stride with 1-tile CLUSTERED data prefetch (L1 sector locality).
// Only change vs R3: W2h is now fragment-layout -> single 16 B frag loads.
// ============================================================================
__global__ __launch_bounds__(256, 2) void edge_kernel(
    const int* __restrict__ row, const int* __restrict__ col,
    const f16* __restrict__ U, const f16* __restrict__ R,
    const f16* __restrict__ W2h, const float* __restrict__ b2,
    const float* __restrict__ W3, const float* __restrict__ b3,
    float* __restrict__ out, int nEdge, int nTiles)
{
    const int tid  = threadIdx.x;
    const int wid  = tid >> 6;
    const int lane = tid & 63;
    const int lg   = lane >> 4;
    const int lr   = lane & 15;

    // ---- resident W2 fragments: frag-contiguous layout, 16 B loads ----
    f16x8 w2f[4][8];
    #pragma unroll
    for (int kt = 0; kt < 4; ++kt)
        #pragma unroll
        for (int nt = 0; nt < 8; ++nt)
            w2f[kt][nt] = *(const f16x8*)(W2h + (size_t)(kt * 8 + nt) * 512 + lane * 8);

    float b2v[8], w3v[8];
    #pragma unroll
    for (int nt = 0; nt < 8; ++nt) {
        b2v[nt] = b2[lr + 16 * nt];
        w3v[nt] = W3[lr + 16 * nt];
    }
    const float b3s = b3[0];

    const int stride = gridDim.x;
    int t = blockIdx.x;
    if (t >= nTiles) return;

    // ---- prologue: gather tile t, prefetch indices for t+stride ----
    int e  = t * 64 + wid * 16 + lr;
    int ec = e < nEdge ? e : (nEdge - 1);
    int ri = row[ec], ci = col[ec];
    f16x8 fr[4];
    #pragma unroll
    for (int kt = 0; kt < 4; ++kt) {
        const f16x8 u = *(const f16x8*)(U + (size_t)ri * H + kt * 32 + lg * 8);
        const f16x8 r = *(const f16x8*)(R + (size_t)ci * H + kt * 32 + lg * 8);
        f16x8 s = u + r;
        #pragma unroll
        for (int i = 0; i < 8; ++i) s[i] = s[i] > (f16)0 ? s[i] : (f16)0;
        fr[kt] = s;
    }
    int riN = 0, ciN = 0;
    {
        const int tn = t + stride;
        if (tn < nTiles) {
            int en = tn * 64 + wid * 16 + lr;
            en = en < nEdge ? en : (nEdge - 1);
            riN = row[en];
            ciN = col[en];
        }
    }

    while (true) {
        const int  tnext = t + stride;
        const bool more  = tnext < nTiles;

        // clustered prefetch: 8 back-to-back gather loads for next tile
        f16x8 gu[4], gr[4];
        if (more) {
            #pragma unroll
            for (int kt = 0; kt < 4; ++kt) {
                gu[kt] = *(const f16x8*)(U + (size_t)riN * H + kt * 32 + lg * 8);
                gr[kt] = *(const f16x8*)(R + (size_t)ciN * H + kt * 32 + lg * 8);
            }
        }
        // prefetch indices two tiles ahead
        int riN2 = 0, ciN2 = 0;
        const int tnn = tnext + stride;
        if (more && tnn < nTiles) {
            int en2 = tnn * 64 + wid * 16 + lr;
            en2 = en2 < nEdge ? en2 : (nEdge - 1);
            riN2 = row[en2];
            ciN2 = col[en2];
        }

        // ---- layer 2 MFMA ----
        f32x4 acc[8];
        #pragma unroll
        for (int nt = 0; nt < 8; ++nt) acc[nt] = (f32x4){b2v[nt], b2v[nt], b2v[nt], b2v[nt]};
        #pragma unroll
        for (int kt = 0; kt < 4; ++kt)
            #pragma unroll
            for (int nt = 0; nt < 8; ++nt)
                acc[nt] = __builtin_amdgcn_mfma_f32_16x16x32_f16(fr[kt], w2f[kt][nt], acc[nt], 0, 0, 0);

        // ---- epilogue: relu -> *w3 -> reduce across 16 lanes -> store ----
        float s0 = 0.f, s1 = 0.f, s2 = 0.f, s3 = 0.f;
        #pragma unroll
        for (int nt = 0; nt < 8; ++nt) {
            const f32x4 a = acc[nt];
            s0 += fmaxf(a[0], 0.f) * w3v[nt];
            s1 += fmaxf(a[1], 0.f) * w3v[nt];
            s2 += fmaxf(a[2], 0.f) * w3v[nt];
            s3 += fmaxf(a[3], 0.f) * w3v[nt];
        }
        #pragma unroll
        for (int m = 1; m < 16; m <<= 1) {
            s0 += __shfl_xor(s0, m);
            s1 += __shfl_xor(s1, m);
            s2 += __shfl_xor(s2, m);
            s3 += __shfl_xor(s3, m);
        }
        if (lr == 0) {
            const int ebase = t * 64 + wid * 16 + lg * 4;
            if (ebase + 0 < nEdge) out[ebase + 0] = s0 + b3s;
            if (ebase + 1 < nEdge) out[ebase + 1] = s1 + b3s;
            if (ebase + 2 < nEdge) out[ebase + 2] = s2 + b3s;
            if (ebase + 3 < nEdge) out[ebase + 3] = s3 + b3s;
        }

        if (!more) break;
        #pragma unroll
        for (int kt = 0; kt < 4; ++kt) {
            f16x8 s = gu[kt] + gr[kt];
            #pragma unroll
            for (int i = 0; i < 8; ++i) s[i] = s[i] > (f16)0 ? s[i] : (f16)0;
            fr[kt] = s;
        }
        riN = riN2;
        ciN = ciN2;
        t = tnext;
    }
}

// ============================================================================
// Fallback: round-1 fp32 kernel (used only if ws_size is too small)
// ============================================================================
#define TILE 16
__global__ __launch_bounds__(256) void edgedec_f32(
    const float* __restrict__ z_user, const float* __restrict__ z_rest,
    const int* __restrict__ row, const int* __restrict__ col,
    const float* __restrict__ W1, const float* __restrict__ b1,
    const float* __restrict__ W2, const float* __restrict__ b2,
    const float* __restrict__ W3, const float* __restrict__ b3,
    float* __restrict__ out, int nEdge)
{
    __shared__ float zt[TILE][2 * H];
    __shared__ float h1t[TILE][H];
    __shared__ float part[TILE][16];
    const int tid  = threadIdx.x;
    const int base = blockIdx.x * TILE;
    {
        const int e0 = tid >> 6, half = (tid >> 5) & 1, q = tid & 31;
        #pragma unroll
        for (int it = 0; it < TILE / 4; ++it) {
            const int e = e0 + it * 4, ge = base + e;
            if (ge < nEdge) {
                const float* src = half ? (z_rest + (size_t)col[ge] * H)
                                        : (z_user + (size_t)row[ge] * H);
                *(float4*)&zt[e][half * H + q * 4] = *(const float4*)(src + q * 4);
            }
        }
    }
    __syncthreads();
    const int j = tid & (H - 1), g = tid >> 7;
    float acc[8];
    {
        const float bj = b1[j];
        #pragma unroll
        for (int e = 0; e < 8; ++e) acc[e] = bj;
        const float4* wp = (const float4*)(W1 + (size_t)j * (2 * H));
        for (int k4 = 0; k4 < (2 * H) / 4; ++k4) {
            const float4 w = wp[k4];
            #pragma unroll
            for (int e = 0; e < 8; ++e) {
                const float4 z = *(const float4*)&zt[g * 8 + e][k4 * 4];
                acc[e] = fmaf(w.x, z.x, acc[e]); acc[e] = fmaf(w.y, z.y, acc[e]);
                acc[e] = fmaf(w.z, z.z, acc[e]); acc[e] = fmaf(w.w, z.w, acc[e]);
            }
        }
        #pragma unroll
        for (int e = 0; e < 8; ++e) h1t[g * 8 + e][j] = fmaxf(acc[e], 0.0f);
    }
    __syncthreads();
    {
        const float bj = b2[j];
        #pragma unroll
        for (int e = 0; e < 8; ++e) acc[e] = bj;
        const float4* wp = (const float4*)(W2 + (size_t)j * H);
        for (int k4 = 0; k4 < H / 4; ++k4) {
            const float4 w = wp[k4];
            #pragma unroll
            for (int e = 0; e < 8; ++e) {
                const float4 h = *(const float4*)&h1t[g * 8 + e][k4 * 4];
                acc[e] = fmaf(w.x, h.x, acc[e]); acc[e] = fmaf(w.y, h.y, acc[e]);
                acc[e] = fmaf(w.z, h.z, acc[e]); acc[e] = fmaf(w.w, h.w, acc[e]);
            }
        }
        const float w3j = W3[j];
        __syncthreads();
        #pragma unroll
        for (int e = 0; e < 8; ++e) h1t[g * 8 + e][j] = w3j * fmaxf(acc[e], 0.0f);
    }
    __syncthreads();
    {
        const int e = tid >> 4, p = tid & 15;
        float s = 0.0f;
        #pragma unroll
        for (int i = 0; i < 8; ++i) s += h1t[e][p * 8 + i];
        part[e][p] = s;
    }
    __syncthreads();
    if (tid < TILE) {
        const int ge = base + tid;
        if (ge < nEdge) {
            float s = b3[0];
            #pragma unroll
            for (int i = 0; i < 16; ++i) s += part[tid][i];
            out[ge] = s;
        }
    }
}

extern "C" void kernel_launch(void* const* d_in, const int* in_sizes, int n_in,
                              void* d_out, int out_size, void* d_ws, size_t ws_size,
                              hipStream_t stream) {
    const float* z_user = (const float*)d_in[0];
    const float* z_rest = (const float*)d_in[1];
    const int*   row    = (const int*)d_in[2];
    const int*   col    = (const int*)d_in[3];
    const float* W1     = (const float*)d_in[4];
    const float* b1     = (const float*)d_in[5];
    const float* W2     = (const float*)d_in[6];
    const float* b2     = (const float*)d_in[7];
    const float* W3     = (const float*)d_in[8];
    const float* b3     = (const float*)d_in[9];
    float* out = (float*)d_out;

    const int nU    = in_sizes[0] / H;
    const int nR    = in_sizes[1] / H;
    const int nEdge = in_sizes[2];

    const size_t uBytes  = (size_t)nU * H * sizeof(f16);
    const size_t rBytes  = (size_t)nR * H * sizeof(f16);
    const size_t w2Bytes = (size_t)H * H * sizeof(f16);
    const size_t w1Bytes = (size_t)H * 2 * H * sizeof(f16);
    const size_t need    = uBytes + rBytes + w2Bytes + w1Bytes;

    if (ws_size < need) {
        const int nBlocks = (nEdge + TILE - 1) / TILE;
        hipLaunchKernelGGL(edgedec_f32, dim3(nBlocks), dim3(256), 0, stream,
                           z_user, z_rest, row, col, W1, b1, W2, b2, W3, b3, out, nEdge);
        return;
    }

    f16* U   = (f16*)d_ws;
    f16* R   = (f16*)((char*)d_ws + uBytes);
    f16* W2h = (f16*)((char*)d_ws + uBytes + rBytes);
    f16* W1h = (f16*)((char*)d_ws + uBytes + rBytes + w2Bytes);

    hipLaunchKernelGGL(convert_weights, dim3(24), dim3(256), 0, stream,
                       W1, W2, W1h, W2h);

    const int nUblk = (nU + 63) / 64;
    const int nRblk = (nR + 63) / 64;
    hipLaunchKernelGGL(precompute_kernel, dim3(nUblk + nRblk), dim3(256), 0, stream,
                       z_user, z_rest, W1h, b1, U, R, nU, nR, nUblk);

    const int nTiles = (nEdge + 63) / 64;
    const int grid   = nTiles < 1024 ? nTiles : 1024;
    hipLaunchKernelGGL(edge_kernel, dim3(grid), dim3(256), 0, stream,
                       row, col, U, R, W2h, b2, W3, b3, out, nEdge, nTiles);
}